// Round 3
// baseline (426.964 us; speedup 1.0000x reference)
//
#include <hip/hip_runtime.h>
#include <stdint.h>

#define THREADS 192
#define DIM 9
#define NK 81                // output cols
#define F 81                 // contraction dim (i*9+j), padded to 96
#define NCHUNK 6             // K-chunks of 16 along f
#define TILE 32              // rows per tile (one 32x32x16 MFMA row block)
#define GRID 1536            // 6 blocks/CU x 256 CUs (LDS 24.75 KB -> 6/CU)

typedef __attribute__((ext_vector_type(8))) short short8;   // 8 bf16 bit-patterns
typedef __attribute__((ext_vector_type(16))) float f32x16;  // MFMA 32x32 accumulator
typedef __attribute__((ext_vector_type(4))) float f32x4;

__device__ inline unsigned short f32_bf16(float x) {        // RNE fp32 -> bf16 bits
    unsigned u = __float_as_uint(x);
    u += 0x7FFFu + ((u >> 16) & 1u);
    return (unsigned short)(u >> 16);
}
__device__ inline float bf16_f32(unsigned short h) {
    return __uint_as_float(((unsigned)h) << 16);
}

// v1: wave-sliced MFMA, LDS C-transpose, contiguous dwordx4 stores (r2: -65us)
// v2 (this): shared input staging (3 waves issue identical global_load_lds into
// one block dbuf), s_c double-buffered -> ONE barrier/iter, v_cvt_pk_bf16_f32
// for A-frag conversion (bit-identical RNE), split hi/lo accumulator chains.
__global__ __launch_bounds__(THREADS, 4)
void tp_mfma(const float* __restrict__ in1, const float* __restrict__ in2,
             const float* __restrict__ cb, float* __restrict__ out,
             int nrows, int ntiles) {
    __shared__ __attribute__((aligned(16))) float s_in[2][576];       // 4.6 KB (shared)
    __shared__ __attribute__((aligned(16))) float s_c[2][TILE * NK];  // 20.25 KB

    const int tid  = threadIdx.x;
    const int lane = tid & 63;
    const int wave = tid >> 6;          // column slice: cols [32*wave, 32*wave+32)
    const int l31  = lane & 31;
    const int h    = lane >> 5;
    const int kcol = 32 * wave + l31;

    // ---- Stationary B (= W) fragments, hi+lo bf16 split, in registers ----
    short8 Bhi[NCHUNK], Blo[NCHUNK];
    for (int c = 0; c < NCHUNK; ++c) {
        union { short8 v; unsigned short u[8]; } bh, bl;
        for (int j = 0; j < 8; ++j) {
            int f = c * 16 + h * 8 + j;
            float v = 0.0f;
            if (f < F && kcol < NK) v = cb[kcol * F + f];
            unsigned short hb = f32_bf16(v);
            bh.u[j] = hb;
            bl.u[j] = f32_bf16(v - bf16_f32(hb));
        }
        Bhi[c] = bh.v; Blo[c] = bl.v;
    }

    const unsigned lim16 = (unsigned)nrows * 36u - 16u;  // OOB clamp (16B loads)
    const unsigned lim4  = (unsigned)nrows * 36u - 4u;   // OOB clamp (4B loads)
    const uintptr_t p1 = (uintptr_t)in1;
    const uintptr_t p2 = (uintptr_t)in2;

    // Stage tile t's 2304 B (32 rows of in1 ++ 32 rows of in2) into the SHARED
    // buffer. All 3 waves issue identical loads (same dest, same data): benign
    // redundant LDS writes; each wave's own vmcnt proves its copy landed.
    auto stage = [&](int t, int buf) {
        const unsigned tb = (unsigned)t * 1152u;
        float* dst0 = &s_in[buf][0];
        {   unsigned o = tb + (unsigned)lane * 16u;
            if (o > lim16) o = lim16;
            __builtin_amdgcn_global_load_lds(
                (__attribute__((address_space(1))) void*)(p1 + o),
                (__attribute__((address_space(3))) void*)dst0, 16, 0, 0);
        }
        {   unsigned bb = 1024u + (unsigned)lane * 16u;
            unsigned o1 = tb + bb;          if (o1 > lim16) o1 = lim16;
            unsigned o2 = tb + bb - 1152u;  if (o2 > lim16) o2 = lim16;
            uintptr_t src = (bb < 1152u) ? (p1 + o1) : (p2 + o2);
            __builtin_amdgcn_global_load_lds(
                (__attribute__((address_space(1))) void*)src,
                (__attribute__((address_space(3))) void*)(dst0 + 256), 16, 0, 0);
        }
        {   unsigned o = tb + 896u + (unsigned)lane * 4u;
            if (o > lim4) o = lim4;
            __builtin_amdgcn_global_load_lds(
                (__attribute__((address_space(1))) void*)(p2 + o),
                (__attribute__((address_space(3))) void*)(dst0 + 512), 4, 0, 0);
        }
    };

    int cur = 0;    // parity for BOTH s_in and s_c double buffers
    const int t0 = blockIdx.x;
    if (t0 < ntiles) stage(t0, 0);

    for (int t = t0; t < ntiles; t += gridDim.x) {
        const int tn = t + gridDim.x;
        const bool hasn = (tn < ntiles);
        if (hasn) stage(tn, cur ^ 1);   // prefetch next tile (3 loads)

        // Wait for loads(t). Ops newer than loads(t) in this wave's vmem queue:
        //   stores from previous iter: 4 (only if t > t0)
        //   prefetch loads just issued: 3 (only if hasn)
        if (t == t0) {
            if (hasn) asm volatile("s_waitcnt vmcnt(3)" ::: "memory");
            else      asm volatile("s_waitcnt vmcnt(0)" ::: "memory");
        } else {
            if (hasn) asm volatile("s_waitcnt vmcnt(7)" ::: "memory");
            else      asm volatile("s_waitcnt vmcnt(4)" ::: "memory");
        }
        __builtin_amdgcn_sched_barrier(0);

        const float* sa = &s_in[cur][0];
        float a[DIM], b[DIM];
#pragma unroll
        for (int i = 0; i < DIM; ++i) {
            a[i] = sa[l31 * 9 + i];
            b[i] = sa[288 + l31 * 9 + i];
        }

        // A-fragments: lane (h,l31) needs P[row=l31][f=c*16+8h+j], j=0..7.
        // Static indices for both h-halves, cndmask select, then hardware RNE
        // pack (v_cvt_pk_bf16_f32: low = src0) -- bit-identical to manual RNE.
        short8 A[NCHUNK];
#pragma unroll
        for (int c = 0; c < NCHUNK; ++c) {
            union { short8 v; unsigned d[4]; } av;
#pragma unroll
            for (int k = 0; k < 4; ++k) {
                float vlo, vhi;
                {
                    const int f0 = c * 16 + 2 * k, f1 = f0 + 8;
                    float q0 = (f0 < F) ? a[f0 / 9] * b[f0 % 9] : 0.0f;
                    float q1 = (f1 < F) ? a[f1 / 9] * b[f1 % 9] : 0.0f;
                    vlo = h ? q1 : q0;
                }
                {
                    const int f0 = c * 16 + 2 * k + 1, f1 = f0 + 8;
                    float q0 = (f0 < F) ? a[f0 / 9] * b[f0 % 9] : 0.0f;
                    float q1 = (f1 < F) ? a[f1 / 9] * b[f1 % 9] : 0.0f;
                    vhi = h ? q1 : q0;
                }
                unsigned dw;
                asm("v_cvt_pk_bf16_f32 %0, %1, %2" : "=v"(dw) : "v"(vlo), "v"(vhi));
                av.d[k] = dw;
            }
            A[c] = av.v;
        }

        // Two independent accumulator chains (hi/lo weights) halve the
        // dependent-MFMA latency; summed at the end (16 v_add_f32).
        f32x16 acch = {0.f,0.f,0.f,0.f, 0.f,0.f,0.f,0.f, 0.f,0.f,0.f,0.f, 0.f,0.f,0.f,0.f};
        f32x16 accl = acch;
#pragma unroll
        for (int c = 0; c < NCHUNK; ++c) {
            acch = __builtin_amdgcn_mfma_f32_32x32x16_bf16(A[c], Bhi[c], acch, 0, 0, 0);
            accl = __builtin_amdgcn_mfma_f32_32x32x16_bf16(A[c], Blo[c], accl, 0, 0, 0);
        }

        // ---- C transpose through LDS (dbuf; parity = cur) ----
        // C/D: col = lane&31, row = (r&3) + 8*(r>>2) + 4*h   [m74/m101]
        if (kcol < NK) {
#pragma unroll
            for (int r = 0; r < 16; ++r) {
                const int mrow = (r & 3) + 8 * (r >> 2) + 4 * h;
                s_c[cur][mrow * NK + kcol] = acch[r] + accl[r];
            }
        }
        // ONE barrier per iter. Safety of s_c[cur] reuse two iters later: the
        // lgkmcnt wait required for this iter's store data completes the reads
        // before the NEXT barrier, which happens-before any parity-matched
        // rewrite (writes occur only after that barrier's rendezvous).
        asm volatile("s_waitcnt lgkmcnt(0)\ns_barrier" ::: "memory");

        // ---- Contiguous, aligned output stores ----
        // Tile region: out + t*10368 B, 10368 B = 648 x dwordx4, 64B-aligned.
        const long r0 = (long)t * TILE;
        if (r0 + TILE <= (long)nrows) {            // full tile (always, at B=1M)
            const f32x4* sc4 = (const f32x4*)&s_c[cur][0];
            f32x4* o4 = (f32x4*)(out + r0 * NK);
#pragma unroll
            for (int q = 0; q < 4; ++q) {          // exactly 4 stores per thread
                int idx = tid + q * THREADS;       // 0..767
                int idc = (idx >= 648) ? idx - 648 : idx;  // clamp-dup (same value)
                o4[idc] = sc4[idc];
            }
        } else {                                   // tail tile (not hit at B=1M)
            for (int e = tid; e < TILE * NK; e += THREADS) {
                long g = r0 * NK + e;
                if (g < (long)nrows * NK) out[g] = s_c[cur][e];
            }
        }
        cur ^= 1;
    }
}

extern "C" void kernel_launch(void* const* d_in, const int* in_sizes, int n_in,
                              void* d_out, int out_size, void* d_ws, size_t ws_size,
                              hipStream_t stream) {
    const float* in1 = (const float*)d_in[0];
    const float* in2 = (const float*)d_in[1];
    const float* cb  = (const float*)d_in[2];
    float* out = (float*)d_out;

    int nrows  = in_sizes[0] / DIM;                 // 1048576
    int ntiles = (nrows + TILE - 1) / TILE;         // 32768 (exact, no tail)
    int grid = (GRID < ntiles) ? GRID : ntiles;

    tp_mfma<<<grid, THREADS, 0, stream>>>(in1, in2, cb, out, nrows, ntiles);
}

// Round 4
// 405.791 us; speedup vs baseline: 1.0522x; 1.0522x over previous
//
#include <hip/hip_runtime.h>
#include <stdint.h>

#define THREADS 192
#define DIM 9
#define NK 81                // output cols
#define F 81                 // contraction dim (i*9+j), padded to 96
#define NCHUNK 6             // K-chunks of 16 along f
#define TILE 32              // rows per tile (one 32x32x16 MFMA row block)
#define GRID 1024            // 4 blocks/CU x 256 CUs (LDS 24.75 KB, 12 waves/CU)

typedef __attribute__((ext_vector_type(8))) short short8;   // 8 bf16 bit-patterns
typedef __attribute__((ext_vector_type(16))) float f32x16;  // MFMA 32x32 accumulator
typedef __attribute__((ext_vector_type(4))) float f32x4;

__device__ inline unsigned short f32_bf16(float x) {        // RNE fp32 -> bf16 bits
    unsigned u = __float_as_uint(x);
    u += 0x7FFFu + ((u >> 16) & 1u);
    return (unsigned short)(u >> 16);
}
__device__ inline float bf16_f32(unsigned short h) {
    return __uint_as_float(((unsigned)h) << 16);
}

// v1: wave-sliced MFMA, LDS C-transpose, contiguous dwordx4 stores.
// v2: shared staging, 1 barrier/iter, v_cvt_pk_bf16_f32, split hi/lo acc.
// v3 (this): KILL SPILLS. launch_bounds(192,3) -> 170 VGPR cap (true need
// ~125 after moving the A-frag build inside the MFMA loop so only one av
// fragment is live at a time). Spills inside the loop were adding scratch
// vmem traffic AND compiler-inserted vmcnt waits that drained the counted
// prefetch pipeline (the ~3x-over-roofline mystery of rounds 1-3).
__global__ __launch_bounds__(THREADS, 3)
void tp_mfma(const float* __restrict__ in1, const float* __restrict__ in2,
             const float* __restrict__ cb, float* __restrict__ out,
             int nrows, int ntiles) {
    __shared__ __attribute__((aligned(16))) float s_in[2][576];       // 4.6 KB (shared)
    __shared__ __attribute__((aligned(16))) float s_c[2][TILE * NK];  // 20.25 KB

    const int tid  = threadIdx.x;
    const int lane = tid & 63;
    const int wave = tid >> 6;          // column slice: cols [32*wave, 32*wave+32)
    const int l31  = lane & 31;
    const int h    = lane >> 5;
    const int kcol = 32 * wave + l31;

    // ---- Stationary B (= W) fragments, hi+lo bf16 split, in registers ----
    short8 Bhi[NCHUNK], Blo[NCHUNK];
    for (int c = 0; c < NCHUNK; ++c) {
        union { short8 v; unsigned short u[8]; } bh, bl;
        for (int j = 0; j < 8; ++j) {
            int f = c * 16 + h * 8 + j;
            float v = 0.0f;
            if (f < F && kcol < NK) v = cb[kcol * F + f];
            unsigned short hb = f32_bf16(v);
            bh.u[j] = hb;
            bl.u[j] = f32_bf16(v - bf16_f32(hb));
        }
        Bhi[c] = bh.v; Blo[c] = bl.v;
    }

    const unsigned lim16 = (unsigned)nrows * 36u - 16u;  // OOB clamp (16B loads)
    const unsigned lim4  = (unsigned)nrows * 36u - 4u;   // OOB clamp (4B loads)
    const uintptr_t p1 = (uintptr_t)in1;
    const uintptr_t p2 = (uintptr_t)in2;

    // Stage tile t's 2304 B (32 rows of in1 ++ 32 rows of in2) into the SHARED
    // buffer. All 3 waves issue identical loads (same dest, same data): benign
    // redundant LDS writes; each wave's own vmcnt proves its copy landed.
    auto stage = [&](int t, int buf) {
        const unsigned tb = (unsigned)t * 1152u;
        float* dst0 = &s_in[buf][0];
        {   unsigned o = tb + (unsigned)lane * 16u;
            if (o > lim16) o = lim16;
            __builtin_amdgcn_global_load_lds(
                (__attribute__((address_space(1))) void*)(p1 + o),
                (__attribute__((address_space(3))) void*)dst0, 16, 0, 0);
        }
        {   unsigned bb = 1024u + (unsigned)lane * 16u;
            unsigned o1 = tb + bb;          if (o1 > lim16) o1 = lim16;
            unsigned o2 = tb + bb - 1152u;  if (o2 > lim16) o2 = lim16;
            uintptr_t src = (bb < 1152u) ? (p1 + o1) : (p2 + o2);
            __builtin_amdgcn_global_load_lds(
                (__attribute__((address_space(1))) void*)src,
                (__attribute__((address_space(3))) void*)(dst0 + 256), 16, 0, 0);
        }
        {   unsigned o = tb + 896u + (unsigned)lane * 4u;
            if (o > lim4) o = lim4;
            __builtin_amdgcn_global_load_lds(
                (__attribute__((address_space(1))) void*)(p2 + o),
                (__attribute__((address_space(3))) void*)(dst0 + 512), 4, 0, 0);
        }
    };

    int cur = 0;    // parity for BOTH s_in and s_c double buffers
    const int t0 = blockIdx.x;
    if (t0 < ntiles) stage(t0, 0);

    for (int t = t0; t < ntiles; t += gridDim.x) {
        const int tn = t + gridDim.x;
        const bool hasn = (tn < ntiles);
        if (hasn) stage(tn, cur ^ 1);   // prefetch next tile (3 loads)

        // Wait for loads(t). Ops newer than loads(t) in this wave's vmem queue:
        //   stores from previous iter: 4 (only if t > t0)
        //   prefetch loads just issued: 3 (only if hasn)
        if (t == t0) {
            if (hasn) asm volatile("s_waitcnt vmcnt(3)" ::: "memory");
            else      asm volatile("s_waitcnt vmcnt(0)" ::: "memory");
        } else {
            if (hasn) asm volatile("s_waitcnt vmcnt(7)" ::: "memory");
            else      asm volatile("s_waitcnt vmcnt(4)" ::: "memory");
        }
        __builtin_amdgcn_sched_barrier(0);

        const float* sa = &s_in[cur][0];
        float a[DIM], b[DIM];
#pragma unroll
        for (int i = 0; i < DIM; ++i) {
            a[i] = sa[l31 * 9 + i];
            b[i] = sa[288 + l31 * 9 + i];
        }

        // A-fragment built per chunk INSIDE the MFMA loop (one av live at a
        // time, ~4 VGPRs peak instead of 24). Static indices for both h-halves,
        // cndmask select, hardware RNE pack (bit-identical to manual RNE).
        // Split hi/lo accumulator chains keep MFMA ILP; summed at the end.
        f32x16 acch = {0.f,0.f,0.f,0.f, 0.f,0.f,0.f,0.f, 0.f,0.f,0.f,0.f, 0.f,0.f,0.f,0.f};
        f32x16 accl = acch;
#pragma unroll
        for (int c = 0; c < NCHUNK; ++c) {
            union { short8 v; unsigned d[4]; } av;
#pragma unroll
            for (int k = 0; k < 4; ++k) {
                float vlo, vhi;
                {
                    const int f0 = c * 16 + 2 * k, f1 = f0 + 8;
                    float q0 = (f0 < F) ? a[f0 / 9] * b[f0 % 9] : 0.0f;
                    float q1 = (f1 < F) ? a[f1 / 9] * b[f1 % 9] : 0.0f;
                    vlo = h ? q1 : q0;
                }
                {
                    const int f0 = c * 16 + 2 * k + 1, f1 = f0 + 8;
                    float q0 = (f0 < F) ? a[f0 / 9] * b[f0 % 9] : 0.0f;
                    float q1 = (f1 < F) ? a[f1 / 9] * b[f1 % 9] : 0.0f;
                    vhi = h ? q1 : q0;
                }
                unsigned dw;
                asm("v_cvt_pk_bf16_f32 %0, %1, %2" : "=v"(dw) : "v"(vlo), "v"(vhi));
                av.d[k] = dw;
            }
            acch = __builtin_amdgcn_mfma_f32_32x32x16_bf16(av.v, Bhi[c], acch, 0, 0, 0);
            accl = __builtin_amdgcn_mfma_f32_32x32x16_bf16(av.v, Blo[c], accl, 0, 0, 0);
        }

        // ---- C transpose through LDS (dbuf; parity = cur) ----
        // C/D: col = lane&31, row = (r&3) + 8*(r>>2) + 4*h   [m74/m101]
        if (kcol < NK) {
#pragma unroll
            for (int r = 0; r < 16; ++r) {
                const int mrow = (r & 3) + 8 * (r >> 2) + 4 * h;
                s_c[cur][mrow * NK + kcol] = acch[r] + accl[r];
            }
        }
        // ONE barrier per iter. s_c[cur] reuse two iters later is safe: the
        // lgkmcnt(0) before the NEXT barrier completes this iter's reads, and
        // parity-matched rewrites only occur after that barrier's rendezvous.
        asm volatile("s_waitcnt lgkmcnt(0)\ns_barrier" ::: "memory");

        // ---- Contiguous, aligned output stores ----
        // Tile region: out + t*10368 B, 10368 B = 648 x dwordx4, 64B-aligned.
        const long r0 = (long)t * TILE;
        if (r0 + TILE <= (long)nrows) {            // full tile (always, at B=1M)
            const f32x4* sc4 = (const f32x4*)&s_c[cur][0];
            f32x4* o4 = (f32x4*)(out + r0 * NK);
#pragma unroll
            for (int q = 0; q < 4; ++q) {          // exactly 4 stores per thread
                int idx = tid + q * THREADS;       // 0..767
                int idc = (idx >= 648) ? idx - 648 : idx;  // clamp-dup (same value)
                o4[idc] = sc4[idc];
            }
        } else {                                   // tail tile (not hit at B=1M)
            for (int e = tid; e < TILE * NK; e += THREADS) {
                long g = r0 * NK + e;
                if (g < (long)nrows * NK) out[g] = s_c[cur][e];
            }
        }
        cur ^= 1;
    }
}

extern "C" void kernel_launch(void* const* d_in, const int* in_sizes, int n_in,
                              void* d_out, int out_size, void* d_ws, size_t ws_size,
                              hipStream_t stream) {
    const float* in1 = (const float*)d_in[0];
    const float* in2 = (const float*)d_in[1];
    const float* cb  = (const float*)d_in[2];
    float* out = (float*)d_out;

    int nrows  = in_sizes[0] / DIM;                 // 1048576
    int ntiles = (nrows + TILE - 1) / TILE;         // 32768 (exact, no tail)
    int grid = (GRID < ntiles) ? GRID : ntiles;

    tp_mfma<<<grid, THREADS, 0, stream>>>(in1, in2, cb, out, nrows, ntiles);
}